// Round 17
// baseline (351.605 us; speedup 1.0000x reference)
//
#include <hip/hip_runtime.h>
#include <math.h>

#define NODES 20000
#define EDGES 320000
#define DIN 128
#define HID 256
#define NGRAPH 32
#define NREL 6
#define STR 1088    // Acat row stride in shorts (17*128B)
#define NRG 32      // dst ranges per relation (CSR build)
#define RGN 625     // dsts per range
#define BCAP 11264  // bucket capacity per (rel,rg)
#define BINSLC 4000 // edges per bin block

typedef __attribute__((ext_vector_type(8))) short bf16x8;
typedef __attribute__((ext_vector_type(8))) unsigned short u16x8;
typedef __attribute__((ext_vector_type(4))) unsigned short u16x4;
typedef __attribute__((ext_vector_type(4))) float f32x4;

__device__ __forceinline__ float bf2f(unsigned short u) {
  return __uint_as_float(((unsigned)u) << 16);
}
__device__ __forceinline__ unsigned short f2bf(float f) {
  unsigned u = __float_as_uint(f);
  unsigned r = (u + 0x7fffu + ((u >> 16) & 1u)) >> 16;
  return (unsigned short)r;
}

// f32 -> fp8 e4m3fn, RTNE, flush |x|<2^-6 to 0, clamp 448
__device__ __forceinline__ unsigned char f2fp8(float f) {
  unsigned u = __float_as_uint(f);
  unsigned s = (u >> 24) & 0x80u;
  unsigned a = u & 0x7fffffffu;
  if (a < 0x3c800000u) return (unsigned char)s;
  if (a > 0x43e00000u) a = 0x43e00000u;
  a += 0x7ffffu + ((a >> 20) & 1u);
  unsigned em = (a >> 20) - (120u << 3);
  if (em > 0x7eu) em = 0x7eu;
  return (unsigned char)(s | em);
}
__device__ __forceinline__ float fp82f(unsigned b) {
  unsigned u = ((b & 0x80u) << 24) | ((b & 0x7fu) << 20);
  return __uint_as_float(u) * __uint_as_float(0x7B800000u);  // *2^120
}
__device__ __forceinline__ void fp8x4_acc(unsigned v, float& a0, float& a1, float& a2,
                                          float& a3) {
#if __has_builtin(__builtin_amdgcn_cvt_pk_f32_fp8)
  typedef float f32x2 __attribute__((ext_vector_type(2)));
  f32x2 lo = __builtin_amdgcn_cvt_pk_f32_fp8((int)v, false);
  f32x2 hi = __builtin_amdgcn_cvt_pk_f32_fp8((int)v, true);
  a0 += lo[0];
  a1 += lo[1];
  a2 += hi[0];
  a3 += hi[1];
#else
  a0 += fp82f(v & 0xffu);
  a1 += fp82f((v >> 8) & 0xffu);
  a2 += fp82f((v >> 16) & 0xffu);
  a3 += fp82f(v >> 24);
#endif
}

#define GLDS(g, l)                                                            \
  __builtin_amdgcn_global_load_lds(                                           \
      (const __attribute__((address_space(1))) void*)(g),                     \
      (__attribute__((address_space(3))) void*)(l), 16, 0, 0)

// ---------------- phase A: bin edges by dst-range, coalesced bucket appends ----------------
__global__ __launch_bounds__(256) void k_bin(const int* __restrict__ edges,
                                             unsigned* __restrict__ bucket,
                                             int* __restrict__ gcur) {
  __shared__ unsigned buf[NRG][256];
  __shared__ int cnt[NRG];
  __shared__ int gbaseL[NRG];
  int rel = blockIdx.y;
  for (int i = threadIdx.x; i < NRG; i += 256) cnt[i] = 0;
  __syncthreads();
  const int* srcp = edges + (size_t)rel * 2 * EDGES;
  const int* dstp = srcp + EDGES;
  int base = blockIdx.x * BINSLC;
  for (int i = base + threadIdx.x; i < base + BINSLC; i += 256) {
    int d = __builtin_nontemporal_load(&dstp[i]);
    int s = __builtin_nontemporal_load(&srcp[i]);
    int rg = (unsigned)d / RGN;
    int dl = d - rg * RGN;
    int p = atomicAdd(&cnt[rg], 1);
    if (p < 256) buf[rg][p] = ((unsigned)dl << 16) | (unsigned)s;
  }
  __syncthreads();
  if (threadIdx.x < NRG) {
    int n = min(cnt[threadIdx.x], 256);
    gbaseL[threadIdx.x] = atomicAdd(&gcur[rel * NRG + threadIdx.x], n);
    cnt[threadIdx.x] = n;
  }
  __syncthreads();
  for (int b = 0; b < NRG; ++b) {
    int n = cnt[b];
    unsigned* gb = bucket + ((size_t)rel * NRG + b) * BCAP + gbaseL[b];
    for (int k = threadIdx.x; k < n; k += 256) gb[k] = buf[b][k];
  }
}

// ---------------- phase A2: per-rel exclusive scan of bucket counts ----------------
__global__ void k_base(const int* __restrict__ gcur, int* __restrict__ gbase,
                       int* __restrict__ rowoff) {
  int t = threadIdx.x;  // 64 threads
  for (int rel = 0; rel < NREL; ++rel) {
    int v = (t < NRG) ? gcur[rel * NRG + t] : 0;
    int x = v;
#pragma unroll
    for (int s = 1; s < NRG; s <<= 1) {
      int u = __shfl_up(x, s, 64);
      if (t >= s) x += u;
    }
    if (t < NRG) gbase[rel * NRG + t] = x - v;
    if (t == 0) rowoff[rel * (NODES + 1) + NODES] = EDGES;
  }
}

// ---------------- phase B: per-(rel,rg) hist + scan + scatter, window-local ----------------
__global__ __launch_bounds__(256) void k_scat2(const unsigned* __restrict__ bucket,
                                               const int* __restrict__ gcur,
                                               const int* __restrict__ gbase,
                                               int* __restrict__ rowoff,
                                               unsigned short* __restrict__ csr16) {
  __shared__ int h[RGN];
  __shared__ int wsum[4];
  int rg = blockIdx.x, rel = blockIdx.y;
  int nE = gcur[rel * NRG + rg];
  int base = gbase[rel * NRG + rg];
  for (int i = threadIdx.x; i < RGN; i += 256) h[i] = 0;
  __syncthreads();
  const unsigned* bk = bucket + ((size_t)rel * NRG + rg) * BCAP;
  for (int i = threadIdx.x; i < nE; i += 256) atomicAdd(&h[bk[i] >> 16], 1);
  __syncthreads();
  int t = threadIdx.x, lane = t & 63, w = t >> 6;
  int i0 = t * 3;
  int v0 = (i0 < RGN) ? h[i0] : 0;
  int v1 = (i0 + 1 < RGN) ? h[i0 + 1] : 0;
  int v2 = (i0 + 2 < RGN) ? h[i0 + 2] : 0;
  int ts = v0 + v1 + v2;
  int x = ts;
#pragma unroll
  for (int s = 1; s < 64; s <<= 1) {
    int u = __shfl_up(x, s, 64);
    if (lane >= s) x += u;
  }
  if (lane == 63) wsum[w] = x;
  __syncthreads();
  int wb = 0;
  for (int k = 0; k < w; ++k) wb += wsum[k];
  int excl = base + wb + x - ts;
  int* ro = rowoff + rel * (NODES + 1) + rg * RGN;
  __syncthreads();
  if (i0 < RGN) {
    ro[i0] = excl;
    h[i0] = excl;
  }
  if (i0 + 1 < RGN) {
    ro[i0 + 1] = excl + v0;
    h[i0 + 1] = excl + v0;
  }
  if (i0 + 2 < RGN) {
    ro[i0 + 2] = excl + v0 + v1;
    h[i0 + 2] = excl + v0 + v1;
  }
  __syncthreads();
  unsigned short* cs = csr16 + (size_t)rel * EDGES;
  for (int i = threadIdx.x; i < nE; i += 256) {
    unsigned e = bk[i];
    int p = atomicAdd(&h[e >> 16], 1);
    cs[p] = (unsigned short)(e & 0xffffu);
  }
}

// ---------------- prep: x -> bf16 (vectorized) ----------------
__global__ void k_xcvt(const float* __restrict__ xv, const float* __restrict__ xp,
                       unsigned short* __restrict__ xbf) {
  int idx = blockIdx.x * 256 + threadIdx.x;
  const int ND = NODES * DIN;
  int e0 = idx * 4;
  if (e0 >= 2 * ND) return;
  const float* s = (e0 < ND) ? (xv + e0) : (xp + e0 - ND);
  float4 v = *(const float4*)s;
  u16x4 o;
  o[0] = f2bf(v.x);
  o[1] = f2bf(v.y);
  o[2] = f2bf(v.z);
  o[3] = f2bf(v.w);
  *(u16x4*)(xbf + e0) = o;
}

// ---------------- prep: weight concat transpose -> bf16 ----------------
__global__ void k_wtrans(const float* __restrict__ W_l, const float* __restrict__ W_r,
                         unsigned short* __restrict__ Wt) {
  const int rels[2][3] = {{0, 1, 3}, {2, 4, 5}};
  int kt = blockIdx.x, nt = blockIdx.y, ld = blockIdx.z;
  int layer = ld >> 1, dt = ld & 1;
  __shared__ float sh[16][17];
  int k0 = kt * 16, n0 = nt * 16;
  int seg = k0 >> 8, kk0 = k0 & 255;
  int tx = threadIdx.x, ty = threadIdx.y;
  float v;
  if (seg < 3) {
    v = W_l[(((size_t)layer * NREL + rels[dt][seg]) * HID + kk0 + ty) * HID + n0 + tx];
  } else {
    v = 0.f;
    for (int j = 0; j < 3; ++j)
      v += W_r[(((size_t)layer * NREL + rels[dt][j]) * HID + kk0 + ty) * HID + n0 + tx];
  }
  sh[ty][tx] = v;
  __syncthreads();
  Wt[((size_t)ld * HID + n0 + ty) * 1024 + k0 + tx] = f2bf(sh[tx][ty]);
}

__global__ void k_wembt(const float* __restrict__ W_emb, unsigned short* __restrict__ Wet) {
  int kt = blockIdx.x, nt = blockIdx.y, t = blockIdx.z;
  __shared__ float sh[16][17];
  int k0 = kt * 16, n0 = nt * 16;
  int tx = threadIdx.x, ty = threadIdx.y;
  sh[ty][tx] = W_emb[((size_t)t * DIN + k0 + ty) * HID + n0 + tx];
  __syncthreads();
  Wet[((size_t)t * HID + n0 + ty) * DIN + k0 + tx] = f2bf(sh[tx][ty]);
}

__global__ void k_bsum(const float* __restrict__ b_l, float* __restrict__ bsum) {
  const int rels[2][3] = {{0, 1, 3}, {2, 4, 5}};
  int idx = blockIdx.x * 256 + threadIdx.x;
  if (idx >= 1024) return;
  int layer = idx >> 9, dt = (idx >> 8) & 1, c = idx & 255;
  float s = 0.f;
  for (int j = 0; j < 3; ++j) s += b_l[(layer * NREL + rels[dt][j]) * HID + c];
  bsum[idx] = s;
}

// ---------------- fused aggregation: fp8 full-row gathers, single pass, unroll-8 ----
// grid (8, 313, 3): x = st*4 + rowquarter (XCD-pinned per src type), y = 16-row slab.
__global__ __launch_bounds__(256) void k_agg(const unsigned char* __restrict__ xs8,
                                             unsigned short* __restrict__ a0,
                                             unsigned short* __restrict__ a1,
                                             const int* __restrict__ rowoff,
                                             const unsigned short* __restrict__ csr16) {
  const int dt_of[6] = {0, 0, 1, 0, 1, 1};
  const int seg_of[6] = {0, 1, 0, 2, 1, 2};
  int x = blockIdx.x;
  int st = x >> 2, rq = x & 3;
  int rel = st * 3 + blockIdx.z;
  int dt = dt_of[rel], seg = seg_of[rel];
  const unsigned char* src = xs8 + (size_t)st * NODES * 256;
  unsigned short* dstb = (dt == 0 ? a0 : a1) + seg * 256;
  int lane16 = threadIdx.x & 15;
  int rsub = threadIdx.x >> 4;
  unsigned coff = (unsigned)lane16 * 16u;
  const int* ro = rowoff + rel * (NODES + 1);
  const unsigned short* lst = csr16 + (size_t)rel * EDGES;
  int row = rq * 5000 + blockIdx.y * 16 + rsub;
  if (row >= rq * 5000 + 5000) return;
#define LD(s) (*(const uint4*)(src + ((unsigned)(s) * 256u + coff)))
#define ACCV(v)                                       \
  {                                                   \
    fp8x4_acc((v).x, ac[0], ac[1], ac[2], ac[3]);     \
    fp8x4_acc((v).y, ac[4], ac[5], ac[6], ac[7]);     \
    fp8x4_acc((v).z, ac[8], ac[9], ac[10], ac[11]);   \
    fp8x4_acc((v).w, ac[12], ac[13], ac[14], ac[15]); \
  }
  int o0 = ro[row], o1 = ro[row + 1];
  float ac[16] = {};
  int nb = o1 - o0;
  int nfull = nb >> 3;
  int j = o0;
  if (nfull > 0) {
    unsigned idx[8];
#pragma unroll
    for (int b = 0; b < 8; ++b) idx[b] = (unsigned)lst[j + b];
#pragma unroll 1
    for (int f = 1;; ++f) {
      uint4 v0 = LD(idx[0]), v1 = LD(idx[1]), v2 = LD(idx[2]), v3 = LD(idx[3]);
      uint4 v4 = LD(idx[4]), v5 = LD(idx[5]), v6 = LD(idx[6]), v7 = LD(idx[7]);
      j += 8;
      bool more = (f < nfull);
      if (more) {
#pragma unroll
        for (int b = 0; b < 8; ++b) idx[b] = (unsigned)lst[j + b];
      }
      ACCV(v0);
      ACCV(v1);
      ACCV(v2);
      ACCV(v3);
      ACCV(v4);
      ACCV(v5);
      ACCV(v6);
      ACCV(v7);
      if (!more) break;
    }
  }
  int rem = nb & 7;
  if (rem & 4) {
    unsigned i0 = lst[j], i1 = lst[j + 1], i2 = lst[j + 2], i3 = lst[j + 3];
    uint4 v0 = LD(i0), v1 = LD(i1), v2 = LD(i2), v3 = LD(i3);
    ACCV(v0);
    ACCV(v1);
    ACCV(v2);
    ACCV(v3);
    j += 4;
  }
  if (rem & 2) {
    unsigned i0 = lst[j], i1 = lst[j + 1];
    uint4 v0 = LD(i0), v1 = LD(i1);
    ACCV(v0);
    ACCV(v1);
    j += 2;
  }
  if (rem & 1) {
    uint4 v0 = LD((unsigned)lst[j]);
    ACCV(v0);
  }
  float inv = nb ? 1.f / (float)nb : 0.f;
  u16x8 oa, ob;
#pragma unroll
  for (int e = 0; e < 8; ++e) {
    oa[e] = f2bf(ac[e] * inv);
    ob[e] = f2bf(ac[8 + e] * inv);
  }
  unsigned short* dp = dstb + (size_t)row * STR + lane16 * 16;
  *(u16x8*)dp = oa;
  *(u16x8*)(dp + 8) = ob;
#undef LD
#undef ACCV
}

// ---------------- MFMA bf16 GEMM, BM=128 BN=64 BK=32, dbuf LDS 24KB ----
template <int K, int AS, int OUTMODE>
__global__ __launch_bounds__(256) void k_mfma(const unsigned short* __restrict__ Abase,
                                              const unsigned short* __restrict__ Btbase,
                                              const float* __restrict__ biasbase,
                                              unsigned short* __restrict__ Crawbase,
                                              unsigned short* __restrict__ Cbfbase,
                                              unsigned char* __restrict__ X8base,
                                              float* __restrict__ statsbase) {
  int bid = blockIdx.x;
  int sel = blockIdx.y;
  int bm_i = (bid & 7) + 8 * (bid >> 5);
  int bn_i = (bid >> 3) & 3;
  if (bm_i >= 157) return;
  const unsigned short* A = Abase + (size_t)sel * NODES * AS;
  const unsigned short* Bt = Btbase + (size_t)sel * 256 * K;
  const float* bias = biasbase + sel * 256;
  const int bm = bm_i * 128, bn = bn_i * 64;
  __shared__ unsigned short As[2][128 * 32];
  __shared__ unsigned short Bs[2][64 * 32];
  const int tid = threadIdx.x, lane = tid & 63, w = tid >> 6;
  const int wr = w >> 1, wc = w & 1;
  const int srow = lane >> 2;
  const int schunk = lane & 3;
  const unsigned char* gA[2];
  const unsigned char* gB;
#pragma unroll
  for (int c = 0; c < 2; ++c) {
    int lr = c * 64 + w * 16 + srow;
    int r = bm + lr;
    if (r >= NODES) r = NODES - 1;
    gA[c] = (const unsigned char*)A + (size_t)r * AS * 2 +
            ((schunk ^ ((lr >> 1) & 3)) * 16);
  }
  {
    int lr = w * 16 + srow;
    gB = (const unsigned char*)Bt + (size_t)(bn + lr) * K * 2 +
         ((schunk ^ ((lr >> 1) & 3)) * 16);
  }

  auto stage = [&](int b, int k0) {
    GLDS(gA[0] + 2 * k0, (char*)As[b] + w * 1024);
    GLDS(gA[1] + 2 * k0, (char*)As[b] + 4096 + w * 1024);
    GLDS(gB + 2 * k0, (char*)Bs[b] + w * 1024);
  };

  f32x4 acc[4][2] = {};
  const int ci = lane >> 4;
  stage(0, 0);
  __syncthreads();
  int cur = 0;
  for (int k0 = 0; k0 < K; k0 += 32) {
    if (k0 + 32 < K) stage(cur ^ 1, k0 + 32);
    const unsigned short* Ab = As[cur];
    const unsigned short* Bb = Bs[cur];
    bf16x8 bfr[2];
#pragma unroll
    for (int n = 0; n < 2; ++n) {
      int rb = wc * 32 + n * 16 + (lane & 15);
      bfr[n] = *(const bf16x8*)((const char*)Bb + rb * 64 + ((ci ^ ((rb >> 1) & 3)) * 16));
    }
#pragma unroll
    for (int m = 0; m < 4; ++m) {
      int ra = wr * 64 + m * 16 + (lane & 15);
      bf16x8 afr = *(const bf16x8*)((const char*)Ab + ra * 64 + ((ci ^ ((ra >> 1) & 3)) * 16));
      acc[m][0] = __builtin_amdgcn_mfma_f32_16x16x32_bf16(afr, bfr[0], acc[m][0], 0, 0, 0);
      acc[m][1] = __builtin_amdgcn_mfma_f32_16x16x32_bf16(afr, bfr[1], acc[m][1], 0, 0, 0);
    }
    __syncthreads();
    cur ^= 1;
  }

#pragma unroll
  for (int n = 0; n < 2; ++n) {
    int col = bn + wc * 32 + n * 16 + (lane & 15);
    float bv = bias[col];
    float s = 0.f, s2 = 0.f;
#pragma unroll
    for (int m = 0; m < 4; ++m) {
#pragma unroll
      for (int q = 0; q < 4; ++q) {
        int row = bm + wr * 64 + m * 16 + ((lane >> 4) * 4) + q;
        if (row < NODES) {
          float v = acc[m][n][q] + bv;
          if (OUTMODE == 0) {
            Crawbase[(size_t)sel * NODES * 256 + (size_t)row * 256 + col] = f2bf(v);
            s += v;
            s2 = fmaf(v, v, s2);
          } else {
            Cbfbase[(size_t)sel * NODES * STR + (size_t)row * STR + col] = f2bf(v);
            X8base[(size_t)sel * NODES * 256 + (size_t)row * 256 + col] = f2fp8(v);
          }
        }
      }
    }
    if (OUTMODE == 0) {
      s += __shfl_xor(s, 16);
      s += __shfl_xor(s, 32);
      s2 += __shfl_xor(s2, 16);
      s2 += __shfl_xor(s2, 32);
      if (lane < 16) {
        float* stats = statsbase + sel * 512;
        atomicAdd(&stats[col], s);
        atomicAdd(&stats[256 + col], s2);
      }
    }
  }
}

// ---------------- BN apply (layer 0): bf16 raw -> bf16 + fp8 xs; grid (., 2) ----------------
__global__ __launch_bounds__(256) void k_bnapply(const unsigned short* __restrict__ rawbase,
                                                 const float* __restrict__ statsbase,
                                                 const float* __restrict__ gammabase,
                                                 const float* __restrict__ betabase,
                                                 unsigned short* __restrict__ outbase,
                                                 unsigned char* __restrict__ out8base) {
  int idx = blockIdx.x * 256 + threadIdx.x;
  if (idx >= NODES * 256) return;
  int dt = blockIdx.y;
  const unsigned short* raw = rawbase + (size_t)dt * NODES * 256;
  const float* stats = statsbase + dt * 512;
  const float* gamma = gammabase + dt * 256;
  const float* beta = betabase + dt * 256;
  unsigned short* out = outbase + (size_t)dt * NODES * STR;
  unsigned char* out8 = out8base + (size_t)dt * NODES * 256;
  int c = idx & 255;
  int rrow = idx >> 8;
  const float inv3 = 1.f / 3.f;
  float m = stats[c] * (inv3 / NODES);
  float ex2 = stats[256 + c] * (inv3 * inv3 / NODES);
  float var = ex2 - m * m;
  float v = (bf2f(raw[idx]) * inv3 - m) * rsqrtf(var + 1e-5f) * gamma[c] + beta[c];
  v = fmaxf(v, 0.f);
  out[(size_t)rrow * STR + c] = f2bf(v);
  out8[idx] = f2fp8(v);
}

// ---------------- pooling: segment-scan, branch-free inner loop; grid (512, 2) ----------------
__global__ __launch_bounds__(256) void k_pool(const unsigned short* __restrict__ rawbase,
                                              const float* __restrict__ statsbase,
                                              const float* __restrict__ gammabase,
                                              const float* __restrict__ betabase,
                                              const unsigned short* __restrict__ prevbase,
                                              const int* __restrict__ batch_v,
                                              const int* __restrict__ batch_p,
                                              float* __restrict__ pooledbase,
                                              float* __restrict__ gcntbase) {
  int dt = blockIdx.y;
  const unsigned short* raw = rawbase + (size_t)dt * NODES * 256;
  const float* stats = statsbase + dt * 512;
  const float* gamma = gammabase + dt * 256;
  const float* beta = betabase + dt * 256;
  const unsigned short* prev = prevbase + (size_t)dt * NODES * STR;
  const int* batch = dt ? batch_p : batch_v;
  float* pooled = pooledbase + dt * NGRAPH * 256;
  float* gcnt = gcntbase + dt * NGRAPH;
  int c = threadIdx.x;
  int rows_per = (NODES + gridDim.x - 1) / gridDim.x;
  int r0 = blockIdx.x * rows_per;
  int r1 = min(NODES, r0 + rows_per);
  if (r0 >= NODES) return;
  const float inv3 = 1.f / 3.f;
  float m = stats[c] * (inv3 / NODES);
  float ex2 = stats[256 + c] * (inv3 * inv3 / NODES);
  float rs = rsqrtf(ex2 - m * m + 1e-5f) * gamma[c];
  float bt = beta[c];
  int r = r0;
  while (r < r1) {
    int g = batch[r];
    int e = r + 1;
    while (e < r1 && batch[e] == g) ++e;
    float s = 0.f;
    for (int k = r; k < e; ++k) {
      float v = fmaxf((bf2f(raw[(size_t)k * 256 + c]) * inv3 - m) * rs + bt, 0.f) +
                bf2f(prev[(size_t)k * STR + c]);
      s += v;
    }
    atomicAdd(&pooled[g * 256 + c], s);
    if (c == 0) atomicAdd(&gcnt[g], (float)(e - r));
    r = e;
  }
}

__global__ __launch_bounds__(256) void k_final(const float* __restrict__ pooled,
                                               const float* __restrict__ gcnt,
                                               const float* __restrict__ Wout,
                                               const float* __restrict__ bout,
                                               float* __restrict__ out) {
  int g = blockIdx.x;
  int h = threadIdx.x;
  float cv = fmaxf(gcnt[g], 1.f);
  float cp = fmaxf(gcnt[NGRAPH + g], 1.f);
  float v = pooled[g * 256 + h] / cv * Wout[h] +
            pooled[NGRAPH * 256 + g * 256 + h] / cp * Wout[256 + h];
#pragma unroll
  for (int s = 32; s > 0; s >>= 1) v += __shfl_down(v, s, 64);
  __shared__ float sh[4];
  if ((h & 63) == 0) sh[h >> 6] = v;
  __syncthreads();
  if (h == 0) {
    float t = sh[0] + sh[1] + sh[2] + sh[3] + bout[0];
    out[g] = 1.f / (1.f + expf(-t));
  }
}

// ---------------- host ----------------
extern "C" void kernel_launch(void* const* d_in, const int* in_sizes, int n_in,
                              void* d_out, int out_size, void* d_ws, size_t ws_size,
                              hipStream_t stream) {
  const float* x_vuln = (const float*)d_in[0];
  const float* x_patch = (const float*)d_in[1];
  const float* W_emb = (const float*)d_in[2];
  const float* b_emb = (const float*)d_in[3];
  const float* W_l = (const float*)d_in[4];
  const float* b_l = (const float*)d_in[5];
  const float* W_r = (const float*)d_in[6];
  const float* gamma = (const float*)d_in[7];
  const float* beta = (const float*)d_in[8];
  const float* W_out = (const float*)d_in[9];
  const float* b_out = (const float*)d_in[10];
  const int* edge_index = (const int*)d_in[11];
  const int* batch_vuln = (const int*)d_in[12];
  const int* batch_patch = (const int*)d_in[13];

  char* ws = (char*)d_ws;
  size_t off = 0;
  auto alloc = [&](size_t bytes) -> void* {
    void* p = ws + off;
    off = (off + bytes + 255) & ~(size_t)255;
    return p;
  };
  unsigned short* csr16 = (unsigned short*)alloc((size_t)NREL * EDGES * 2);
  int* rowoff = (int*)alloc((size_t)NREL * (NODES + 1) * 4);
  unsigned short* Acat[2];
  Acat[0] = (unsigned short*)alloc((size_t)NODES * STR * 2);  // contiguous pair
  Acat[1] = (unsigned short*)alloc((size_t)NODES * STR * 2);
  unsigned short* rawbf = (unsigned short*)alloc((size_t)2 * NODES * 256 * 2);
  unsigned char* xs8 = (unsigned char*)alloc((size_t)2 * NODES * 256);  // fp8 shadow
  unsigned short* xbf = (unsigned short*)alloc((size_t)2 * NODES * DIN * 2);
  unsigned short* Wt = (unsigned short*)alloc((size_t)4 * 256 * 1024 * 2);
  unsigned short* Wet = (unsigned short*)alloc((size_t)2 * 256 * DIN * 2);
  float* bsum = (float*)alloc(1024 * 4);
  // bucket aliases rawbf (8.65MB <= 20.5MB): consumed by k_scat2 before the first
  // layer-GEMM writes rawbf — stream-ordered, safe.
  unsigned* bucket = (unsigned*)rawbf;
  int* gbase = (int*)alloc((size_t)NREL * NRG * 4);
  // ---- contiguous zero region ----
  size_t zoff0 = off;
  int* gcur = (int*)alloc((size_t)NREL * NRG * 4);
  float* stats = (float*)alloc((size_t)2 * 2 * 512 * 4);
  float* pooled = (float*)alloc((size_t)2 * NGRAPH * 256 * 4);
  float* gcnt = (float*)alloc((size_t)2 * NGRAPH * 4);
  size_t zbytes = off - zoff0;
  hipMemsetAsync(ws + zoff0, 0, zbytes, stream);

  k_bin<<<dim3(EDGES / BINSLC, NREL), 256, 0, stream>>>(edge_index, bucket, gcur);
  k_base<<<1, 64, 0, stream>>>(gcur, gbase, rowoff);
  k_scat2<<<dim3(NRG, NREL), 256, 0, stream>>>(bucket, gcur, gbase, rowoff, csr16);

  k_xcvt<<<(2 * NODES * DIN / 4 + 255) / 256, 256, 0, stream>>>(x_vuln, x_patch, xbf);
  k_wtrans<<<dim3(64, 16, 4), dim3(16, 16), 0, stream>>>(W_l, W_r, Wt);
  k_wembt<<<dim3(8, 16, 2), dim3(16, 16), 0, stream>>>(W_emb, Wet);
  k_bsum<<<4, 256, 0, stream>>>(b_l, bsum);

  // embed both node types in one dispatch (writes bf16 seg3 + fp8 shadow)
  k_mfma<DIN, DIN, 1><<<dim3(640, 2), 256, 0, stream>>>(xbf, Wet, b_emb, nullptr,
                                                        Acat[0] + 768, xs8, nullptr);

  for (int layer = 0; layer < 2; ++layer) {
    k_agg<<<dim3(8, 313, 3), 256, 0, stream>>>(xs8, Acat[0], Acat[1], rowoff, csr16);
    k_mfma<1024, STR, 0><<<dim3(640, 2), 256, 0, stream>>>(
        Acat[0], Wt + (size_t)layer * 2 * 256 * 1024, bsum + layer * 512, rawbf,
        nullptr, nullptr, stats + layer * 1024);
    if (layer == 0)
      k_bnapply<<<dim3((NODES * 256 + 255) / 256, 2), 256, 0, stream>>>(
          rawbf, stats, gamma, beta, Acat[0] + 768, xs8);
  }

  k_pool<<<dim3(512, 2), 256, 0, stream>>>(rawbf, stats + 2 * 512, gamma + 2 * 256,
                                           beta + 2 * 256, Acat[0] + 768, batch_vuln,
                                           batch_patch, pooled, gcnt);
  k_final<<<NGRAPH, 256, 0, stream>>>(pooled, gcnt, W_out, b_out, (float*)d_out);
}

// Round 18
// 322.418 us; speedup vs baseline: 1.0905x; 1.0905x over previous
//
#include <hip/hip_runtime.h>
#include <math.h>

#define NODES 20000
#define EDGES 320000
#define DIN 128
#define HID 256
#define NGRAPH 32
#define NREL 6
#define STR 1088    // Acat row stride in shorts (17*128B)
#define NRG 32      // dst ranges per relation (CSR build)
#define RGN 625     // dsts per range
#define BCAP 11264  // bucket capacity per (rel,rg)
#define BINSLC 4000 // edges per bin block

typedef __attribute__((ext_vector_type(8))) short bf16x8;
typedef __attribute__((ext_vector_type(8))) unsigned short u16x8;
typedef __attribute__((ext_vector_type(4))) unsigned short u16x4;
typedef __attribute__((ext_vector_type(4))) float f32x4;

__device__ __forceinline__ float bf2f(unsigned short u) {
  return __uint_as_float(((unsigned)u) << 16);
}
__device__ __forceinline__ unsigned short f2bf(float f) {
  unsigned u = __float_as_uint(f);
  unsigned r = (u + 0x7fffu + ((u >> 16) & 1u)) >> 16;
  return (unsigned short)r;
}

// f32 -> fp8 e4m3fn, RTNE, flush |x|<2^-6 to 0, clamp 448
__device__ __forceinline__ unsigned char f2fp8(float f) {
  unsigned u = __float_as_uint(f);
  unsigned s = (u >> 24) & 0x80u;
  unsigned a = u & 0x7fffffffu;
  if (a < 0x3c800000u) return (unsigned char)s;
  if (a > 0x43e00000u) a = 0x43e00000u;
  a += 0x7ffffu + ((a >> 20) & 1u);
  unsigned em = (a >> 20) - (120u << 3);
  if (em > 0x7eu) em = 0x7eu;
  return (unsigned char)(s | em);
}
__device__ __forceinline__ float fp82f(unsigned b) {
  unsigned u = ((b & 0x80u) << 24) | ((b & 0x7fu) << 20);
  return __uint_as_float(u) * __uint_as_float(0x7B800000u);  // *2^120
}
__device__ __forceinline__ void fp8x4_acc(unsigned v, float& a0, float& a1, float& a2,
                                          float& a3) {
#if __has_builtin(__builtin_amdgcn_cvt_pk_f32_fp8)
  typedef float f32x2 __attribute__((ext_vector_type(2)));
  f32x2 lo = __builtin_amdgcn_cvt_pk_f32_fp8((int)v, false);
  f32x2 hi = __builtin_amdgcn_cvt_pk_f32_fp8((int)v, true);
  a0 += lo[0];
  a1 += lo[1];
  a2 += hi[0];
  a3 += hi[1];
#else
  a0 += fp82f(v & 0xffu);
  a1 += fp82f((v >> 8) & 0xffu);
  a2 += fp82f((v >> 16) & 0xffu);
  a3 += fp82f(v >> 24);
#endif
}

#define GLDS(g, l)                                                            \
  __builtin_amdgcn_global_load_lds(                                           \
      (const __attribute__((address_space(1))) void*)(g),                     \
      (__attribute__((address_space(3))) void*)(l), 16, 0, 0)

// ---------------- phase A: bin edges by dst-range, coalesced bucket appends ----------------
__global__ __launch_bounds__(256) void k_bin(const int* __restrict__ edges,
                                             unsigned* __restrict__ bucket,
                                             int* __restrict__ gcur) {
  __shared__ unsigned buf[NRG][256];
  __shared__ int cnt[NRG];
  __shared__ int gbaseL[NRG];
  int rel = blockIdx.y;
  for (int i = threadIdx.x; i < NRG; i += 256) cnt[i] = 0;
  __syncthreads();
  const int* srcp = edges + (size_t)rel * 2 * EDGES;
  const int* dstp = srcp + EDGES;
  int base = blockIdx.x * BINSLC;
  for (int i = base + threadIdx.x; i < base + BINSLC; i += 256) {
    int d = __builtin_nontemporal_load(&dstp[i]);
    int s = __builtin_nontemporal_load(&srcp[i]);
    int rg = (unsigned)d / RGN;
    int dl = d - rg * RGN;
    int p = atomicAdd(&cnt[rg], 1);
    if (p < 256) buf[rg][p] = ((unsigned)dl << 16) | (unsigned)s;
  }
  __syncthreads();
  if (threadIdx.x < NRG) {
    int n = min(cnt[threadIdx.x], 256);
    gbaseL[threadIdx.x] = atomicAdd(&gcur[rel * NRG + threadIdx.x], n);
    cnt[threadIdx.x] = n;
  }
  __syncthreads();
  for (int b = 0; b < NRG; ++b) {
    int n = cnt[b];
    unsigned* gb = bucket + ((size_t)rel * NRG + b) * BCAP + gbaseL[b];
    for (int k = threadIdx.x; k < n; k += 256) gb[k] = buf[b][k];
  }
}

// ---------------- phase A2: per-rel exclusive scan of bucket counts ----------------
__global__ void k_base(const int* __restrict__ gcur, int* __restrict__ gbase,
                       int* __restrict__ rowoff) {
  int t = threadIdx.x;  // 64 threads
  for (int rel = 0; rel < NREL; ++rel) {
    int v = (t < NRG) ? gcur[rel * NRG + t] : 0;
    int x = v;
#pragma unroll
    for (int s = 1; s < NRG; s <<= 1) {
      int u = __shfl_up(x, s, 64);
      if (t >= s) x += u;
    }
    if (t < NRG) gbase[rel * NRG + t] = x - v;
    if (t == 0) rowoff[rel * (NODES + 1) + NODES] = EDGES;
  }
}

// ---------------- phase B: per-(rel,rg) hist + scan + scatter, window-local ----------------
__global__ __launch_bounds__(256) void k_scat2(const unsigned* __restrict__ bucket,
                                               const int* __restrict__ gcur,
                                               const int* __restrict__ gbase,
                                               int* __restrict__ rowoff,
                                               unsigned short* __restrict__ csr16) {
  __shared__ int h[RGN];
  __shared__ int wsum[4];
  int rg = blockIdx.x, rel = blockIdx.y;
  int nE = gcur[rel * NRG + rg];
  int base = gbase[rel * NRG + rg];
  for (int i = threadIdx.x; i < RGN; i += 256) h[i] = 0;
  __syncthreads();
  const unsigned* bk = bucket + ((size_t)rel * NRG + rg) * BCAP;
  for (int i = threadIdx.x; i < nE; i += 256) atomicAdd(&h[bk[i] >> 16], 1);
  __syncthreads();
  int t = threadIdx.x, lane = t & 63, w = t >> 6;
  int i0 = t * 3;
  int v0 = (i0 < RGN) ? h[i0] : 0;
  int v1 = (i0 + 1 < RGN) ? h[i0 + 1] : 0;
  int v2 = (i0 + 2 < RGN) ? h[i0 + 2] : 0;
  int ts = v0 + v1 + v2;
  int x = ts;
#pragma unroll
  for (int s = 1; s < 64; s <<= 1) {
    int u = __shfl_up(x, s, 64);
    if (lane >= s) x += u;
  }
  if (lane == 63) wsum[w] = x;
  __syncthreads();
  int wb = 0;
  for (int k = 0; k < w; ++k) wb += wsum[k];
  int excl = base + wb + x - ts;
  int* ro = rowoff + rel * (NODES + 1) + rg * RGN;
  __syncthreads();
  if (i0 < RGN) {
    ro[i0] = excl;
    h[i0] = excl;
  }
  if (i0 + 1 < RGN) {
    ro[i0 + 1] = excl + v0;
    h[i0 + 1] = excl + v0;
  }
  if (i0 + 2 < RGN) {
    ro[i0 + 2] = excl + v0 + v1;
    h[i0 + 2] = excl + v0 + v1;
  }
  __syncthreads();
  unsigned short* cs = csr16 + (size_t)rel * EDGES;
  for (int i = threadIdx.x; i < nE; i += 256) {
    unsigned e = bk[i];
    int p = atomicAdd(&h[e >> 16], 1);
    cs[p] = (unsigned short)(e & 0xffffu);
  }
}

// ---------------- prep: x -> bf16 (vectorized) ----------------
__global__ void k_xcvt(const float* __restrict__ xv, const float* __restrict__ xp,
                       unsigned short* __restrict__ xbf) {
  int idx = blockIdx.x * 256 + threadIdx.x;
  const int ND = NODES * DIN;
  int e0 = idx * 4;
  if (e0 >= 2 * ND) return;
  const float* s = (e0 < ND) ? (xv + e0) : (xp + e0 - ND);
  float4 v = *(const float4*)s;
  u16x4 o;
  o[0] = f2bf(v.x);
  o[1] = f2bf(v.y);
  o[2] = f2bf(v.z);
  o[3] = f2bf(v.w);
  *(u16x4*)(xbf + e0) = o;
}

// ---------------- prep: weight concat transpose -> bf16 ----------------
__global__ void k_wtrans(const float* __restrict__ W_l, const float* __restrict__ W_r,
                         unsigned short* __restrict__ Wt) {
  const int rels[2][3] = {{0, 1, 3}, {2, 4, 5}};
  int kt = blockIdx.x, nt = blockIdx.y, ld = blockIdx.z;
  int layer = ld >> 1, dt = ld & 1;
  __shared__ float sh[16][17];
  int k0 = kt * 16, n0 = nt * 16;
  int seg = k0 >> 8, kk0 = k0 & 255;
  int tx = threadIdx.x, ty = threadIdx.y;
  float v;
  if (seg < 3) {
    v = W_l[(((size_t)layer * NREL + rels[dt][seg]) * HID + kk0 + ty) * HID + n0 + tx];
  } else {
    v = 0.f;
    for (int j = 0; j < 3; ++j)
      v += W_r[(((size_t)layer * NREL + rels[dt][j]) * HID + kk0 + ty) * HID + n0 + tx];
  }
  sh[ty][tx] = v;
  __syncthreads();
  Wt[((size_t)ld * HID + n0 + ty) * 1024 + k0 + tx] = f2bf(sh[tx][ty]);
}

__global__ void k_wembt(const float* __restrict__ W_emb, unsigned short* __restrict__ Wet) {
  int kt = blockIdx.x, nt = blockIdx.y, t = blockIdx.z;
  __shared__ float sh[16][17];
  int k0 = kt * 16, n0 = nt * 16;
  int tx = threadIdx.x, ty = threadIdx.y;
  sh[ty][tx] = W_emb[((size_t)t * DIN + k0 + ty) * HID + n0 + tx];
  __syncthreads();
  Wet[((size_t)t * HID + n0 + ty) * DIN + k0 + tx] = f2bf(sh[tx][ty]);
}

__global__ void k_bsum(const float* __restrict__ b_l, float* __restrict__ bsum) {
  const int rels[2][3] = {{0, 1, 3}, {2, 4, 5}};
  int idx = blockIdx.x * 256 + threadIdx.x;
  if (idx >= 1024) return;
  int layer = idx >> 9, dt = (idx >> 8) & 1, c = idx & 255;
  float s = 0.f;
  for (int j = 0; j < 3; ++j) s += b_l[(layer * NREL + rels[dt][j]) * HID + c];
  bsum[idx] = s;
}

// ---------------- fused aggregation: fp8 full-row gathers, single pass, unroll-4 ----
// grid (8, 313, 3): x = st*4 + rowquarter (XCD-pinned per src type), y = 16-row slab.
__global__ __launch_bounds__(256) void k_agg(const unsigned char* __restrict__ xs8,
                                             unsigned short* __restrict__ a0,
                                             unsigned short* __restrict__ a1,
                                             const int* __restrict__ rowoff,
                                             const unsigned short* __restrict__ csr16) {
  const int dt_of[6] = {0, 0, 1, 0, 1, 1};
  const int seg_of[6] = {0, 1, 0, 2, 1, 2};
  int x = blockIdx.x;
  int st = x >> 2, rq = x & 3;
  int rel = st * 3 + blockIdx.z;
  int dt = dt_of[rel], seg = seg_of[rel];
  const unsigned char* src = xs8 + (size_t)st * NODES * 256;
  unsigned short* dstb = (dt == 0 ? a0 : a1) + seg * 256;
  int lane16 = threadIdx.x & 15;
  int rsub = threadIdx.x >> 4;
  unsigned coff = (unsigned)lane16 * 16u;
  const int* ro = rowoff + rel * (NODES + 1);
  const unsigned short* lst = csr16 + (size_t)rel * EDGES;
  int row = rq * 5000 + blockIdx.y * 16 + rsub;
  if (row >= rq * 5000 + 5000) return;
#define LD(s) (*(const uint4*)(src + ((unsigned)(s) * 256u + coff)))
#define ACCV(v)                                       \
  {                                                   \
    fp8x4_acc((v).x, ac[0], ac[1], ac[2], ac[3]);     \
    fp8x4_acc((v).y, ac[4], ac[5], ac[6], ac[7]);     \
    fp8x4_acc((v).z, ac[8], ac[9], ac[10], ac[11]);   \
    fp8x4_acc((v).w, ac[12], ac[13], ac[14], ac[15]); \
  }
  int o0 = ro[row], o1 = ro[row + 1];
  float ac[16] = {};
  int nb = o1 - o0;
  int nfull = nb >> 2;
  int j = o0;
  if (nfull > 0) {
    unsigned idx[4];
#pragma unroll
    for (int b = 0; b < 4; ++b) idx[b] = (unsigned)lst[j + b];
#pragma unroll 1
    for (int f = 1;; ++f) {
      uint4 v0 = LD(idx[0]), v1 = LD(idx[1]), v2 = LD(idx[2]), v3 = LD(idx[3]);
      j += 4;
      bool more = (f < nfull);
      if (more) {
#pragma unroll
        for (int b = 0; b < 4; ++b) idx[b] = (unsigned)lst[j + b];
      }
      ACCV(v0);
      ACCV(v1);
      ACCV(v2);
      ACCV(v3);
      if (!more) break;
    }
  }
  int rem = nb & 3;
  if (rem & 2) {
    unsigned i0 = lst[j], i1 = lst[j + 1];
    uint4 v0 = LD(i0), v1 = LD(i1);
    ACCV(v0);
    ACCV(v1);
    j += 2;
  }
  if (rem & 1) {
    uint4 v0 = LD((unsigned)lst[j]);
    ACCV(v0);
  }
  float inv = nb ? 1.f / (float)nb : 0.f;
  u16x8 oa, ob;
#pragma unroll
  for (int e = 0; e < 8; ++e) {
    oa[e] = f2bf(ac[e] * inv);
    ob[e] = f2bf(ac[8 + e] * inv);
  }
  unsigned short* dp = dstb + (size_t)row * STR + lane16 * 16;
  *(u16x8*)dp = oa;
  *(u16x8*)(dp + 8) = ob;
#undef LD
#undef ACCV
}

// ---------------- MFMA bf16 GEMM, BM=128 BN=64 BK=32, dbuf LDS 24KB ----
template <int K, int AS, int OUTMODE>
__global__ __launch_bounds__(256) void k_mfma(const unsigned short* __restrict__ Abase,
                                              const unsigned short* __restrict__ Btbase,
                                              const float* __restrict__ biasbase,
                                              unsigned short* __restrict__ Crawbase,
                                              unsigned short* __restrict__ Cbfbase,
                                              unsigned char* __restrict__ X8base,
                                              float* __restrict__ statsbase) {
  int bid = blockIdx.x;
  int sel = blockIdx.y;
  int bm_i = (bid & 7) + 8 * (bid >> 5);
  int bn_i = (bid >> 3) & 3;
  if (bm_i >= 157) return;
  const unsigned short* A = Abase + (size_t)sel * NODES * AS;
  const unsigned short* Bt = Btbase + (size_t)sel * 256 * K;
  const float* bias = biasbase + sel * 256;
  const int bm = bm_i * 128, bn = bn_i * 64;
  __shared__ unsigned short As[2][128 * 32];
  __shared__ unsigned short Bs[2][64 * 32];
  const int tid = threadIdx.x, lane = tid & 63, w = tid >> 6;
  const int wr = w >> 1, wc = w & 1;
  const int srow = lane >> 2;
  const int schunk = lane & 3;
  const unsigned char* gA[2];
  const unsigned char* gB;
#pragma unroll
  for (int c = 0; c < 2; ++c) {
    int lr = c * 64 + w * 16 + srow;
    int r = bm + lr;
    if (r >= NODES) r = NODES - 1;
    gA[c] = (const unsigned char*)A + (size_t)r * AS * 2 +
            ((schunk ^ ((lr >> 1) & 3)) * 16);
  }
  {
    int lr = w * 16 + srow;
    gB = (const unsigned char*)Bt + (size_t)(bn + lr) * K * 2 +
         ((schunk ^ ((lr >> 1) & 3)) * 16);
  }

  auto stage = [&](int b, int k0) {
    GLDS(gA[0] + 2 * k0, (char*)As[b] + w * 1024);
    GLDS(gA[1] + 2 * k0, (char*)As[b] + 4096 + w * 1024);
    GLDS(gB + 2 * k0, (char*)Bs[b] + w * 1024);
  };

  f32x4 acc[4][2] = {};
  const int ci = lane >> 4;
  stage(0, 0);
  __syncthreads();
  int cur = 0;
  for (int k0 = 0; k0 < K; k0 += 32) {
    if (k0 + 32 < K) stage(cur ^ 1, k0 + 32);
    const unsigned short* Ab = As[cur];
    const unsigned short* Bb = Bs[cur];
    bf16x8 bfr[2];
#pragma unroll
    for (int n = 0; n < 2; ++n) {
      int rb = wc * 32 + n * 16 + (lane & 15);
      bfr[n] = *(const bf16x8*)((const char*)Bb + rb * 64 + ((ci ^ ((rb >> 1) & 3)) * 16));
    }
#pragma unroll
    for (int m = 0; m < 4; ++m) {
      int ra = wr * 64 + m * 16 + (lane & 15);
      bf16x8 afr = *(const bf16x8*)((const char*)Ab + ra * 64 + ((ci ^ ((ra >> 1) & 3)) * 16));
      acc[m][0] = __builtin_amdgcn_mfma_f32_16x16x32_bf16(afr, bfr[0], acc[m][0], 0, 0, 0);
      acc[m][1] = __builtin_amdgcn_mfma_f32_16x16x32_bf16(afr, bfr[1], acc[m][1], 0, 0, 0);
    }
    __syncthreads();
    cur ^= 1;
  }

#pragma unroll
  for (int n = 0; n < 2; ++n) {
    int col = bn + wc * 32 + n * 16 + (lane & 15);
    float bv = bias[col];
    float s = 0.f, s2 = 0.f;
#pragma unroll
    for (int m = 0; m < 4; ++m) {
#pragma unroll
      for (int q = 0; q < 4; ++q) {
        int row = bm + wr * 64 + m * 16 + ((lane >> 4) * 4) + q;
        if (row < NODES) {
          float v = acc[m][n][q] + bv;
          if (OUTMODE == 0) {
            Crawbase[(size_t)sel * NODES * 256 + (size_t)row * 256 + col] = f2bf(v);
            s += v;
            s2 = fmaf(v, v, s2);
          } else {
            Cbfbase[(size_t)sel * NODES * STR + (size_t)row * STR + col] = f2bf(v);
            X8base[(size_t)sel * NODES * 256 + (size_t)row * 256 + col] = f2fp8(v);
          }
        }
      }
    }
    if (OUTMODE == 0) {
      s += __shfl_xor(s, 16);
      s += __shfl_xor(s, 32);
      s2 += __shfl_xor(s2, 16);
      s2 += __shfl_xor(s2, 32);
      if (lane < 16) {
        float* stats = statsbase + sel * 512;
        atomicAdd(&stats[col], s);
        atomicAdd(&stats[256 + col], s2);
      }
    }
  }
}

// ---------------- BN apply (layer 0): bf16 raw -> bf16 + fp8 xs; grid (., 2) ----------------
__global__ __launch_bounds__(256) void k_bnapply(const unsigned short* __restrict__ rawbase,
                                                 const float* __restrict__ statsbase,
                                                 const float* __restrict__ gammabase,
                                                 const float* __restrict__ betabase,
                                                 unsigned short* __restrict__ outbase,
                                                 unsigned char* __restrict__ out8base) {
  int idx = blockIdx.x * 256 + threadIdx.x;
  if (idx >= NODES * 256) return;
  int dt = blockIdx.y;
  const unsigned short* raw = rawbase + (size_t)dt * NODES * 256;
  const float* stats = statsbase + dt * 512;
  const float* gamma = gammabase + dt * 256;
  const float* beta = betabase + dt * 256;
  unsigned short* out = outbase + (size_t)dt * NODES * STR;
  unsigned char* out8 = out8base + (size_t)dt * NODES * 256;
  int c = idx & 255;
  int rrow = idx >> 8;
  const float inv3 = 1.f / 3.f;
  float m = stats[c] * (inv3 / NODES);
  float ex2 = stats[256 + c] * (inv3 * inv3 / NODES);
  float var = ex2 - m * m;
  float v = (bf2f(raw[idx]) * inv3 - m) * rsqrtf(var + 1e-5f) * gamma[c] + beta[c];
  v = fmaxf(v, 0.f);
  out[(size_t)rrow * STR + c] = f2bf(v);
  out8[idx] = f2fp8(v);
}

// ---------------- pooling: segment-scan, branch-free inner loop; grid (512, 2) ----------------
__global__ __launch_bounds__(256) void k_pool(const unsigned short* __restrict__ rawbase,
                                              const float* __restrict__ statsbase,
                                              const float* __restrict__ gammabase,
                                              const float* __restrict__ betabase,
                                              const unsigned short* __restrict__ prevbase,
                                              const int* __restrict__ batch_v,
                                              const int* __restrict__ batch_p,
                                              float* __restrict__ pooledbase,
                                              float* __restrict__ gcntbase) {
  int dt = blockIdx.y;
  const unsigned short* raw = rawbase + (size_t)dt * NODES * 256;
  const float* stats = statsbase + dt * 512;
  const float* gamma = gammabase + dt * 256;
  const float* beta = betabase + dt * 256;
  const unsigned short* prev = prevbase + (size_t)dt * NODES * STR;
  const int* batch = dt ? batch_p : batch_v;
  float* pooled = pooledbase + dt * NGRAPH * 256;
  float* gcnt = gcntbase + dt * NGRAPH;
  int c = threadIdx.x;
  int rows_per = (NODES + gridDim.x - 1) / gridDim.x;
  int r0 = blockIdx.x * rows_per;
  int r1 = min(NODES, r0 + rows_per);
  if (r0 >= NODES) return;
  const float inv3 = 1.f / 3.f;
  float m = stats[c] * (inv3 / NODES);
  float ex2 = stats[256 + c] * (inv3 * inv3 / NODES);
  float rs = rsqrtf(ex2 - m * m + 1e-5f) * gamma[c];
  float bt = beta[c];
  int r = r0;
  while (r < r1) {
    int g = batch[r];
    int e = r + 1;
    while (e < r1 && batch[e] == g) ++e;
    float s = 0.f;
    for (int k = r; k < e; ++k) {
      float v = fmaxf((bf2f(raw[(size_t)k * 256 + c]) * inv3 - m) * rs + bt, 0.f) +
                bf2f(prev[(size_t)k * STR + c]);
      s += v;
    }
    atomicAdd(&pooled[g * 256 + c], s);
    if (c == 0) atomicAdd(&gcnt[g], (float)(e - r));
    r = e;
  }
}

__global__ __launch_bounds__(256) void k_final(const float* __restrict__ pooled,
                                               const float* __restrict__ gcnt,
                                               const float* __restrict__ Wout,
                                               const float* __restrict__ bout,
                                               float* __restrict__ out) {
  int g = blockIdx.x;
  int h = threadIdx.x;
  float cv = fmaxf(gcnt[g], 1.f);
  float cp = fmaxf(gcnt[NGRAPH + g], 1.f);
  float v = pooled[g * 256 + h] / cv * Wout[h] +
            pooled[NGRAPH * 256 + g * 256 + h] / cp * Wout[256 + h];
#pragma unroll
  for (int s = 32; s > 0; s >>= 1) v += __shfl_down(v, s, 64);
  __shared__ float sh[4];
  if ((h & 63) == 0) sh[h >> 6] = v;
  __syncthreads();
  if (h == 0) {
    float t = sh[0] + sh[1] + sh[2] + sh[3] + bout[0];
    out[g] = 1.f / (1.f + expf(-t));
  }
}

// ---------------- host ----------------
extern "C" void kernel_launch(void* const* d_in, const int* in_sizes, int n_in,
                              void* d_out, int out_size, void* d_ws, size_t ws_size,
                              hipStream_t stream) {
  const float* x_vuln = (const float*)d_in[0];
  const float* x_patch = (const float*)d_in[1];
  const float* W_emb = (const float*)d_in[2];
  const float* b_emb = (const float*)d_in[3];
  const float* W_l = (const float*)d_in[4];
  const float* b_l = (const float*)d_in[5];
  const float* W_r = (const float*)d_in[6];
  const float* gamma = (const float*)d_in[7];
  const float* beta = (const float*)d_in[8];
  const float* W_out = (const float*)d_in[9];
  const float* b_out = (const float*)d_in[10];
  const int* edge_index = (const int*)d_in[11];
  const int* batch_vuln = (const int*)d_in[12];
  const int* batch_patch = (const int*)d_in[13];

  char* ws = (char*)d_ws;
  size_t off = 0;
  auto alloc = [&](size_t bytes) -> void* {
    void* p = ws + off;
    off = (off + bytes + 255) & ~(size_t)255;
    return p;
  };
  unsigned short* csr16 = (unsigned short*)alloc((size_t)NREL * EDGES * 2);
  int* rowoff = (int*)alloc((size_t)NREL * (NODES + 1) * 4);
  unsigned short* Acat[2];
  Acat[0] = (unsigned short*)alloc((size_t)NODES * STR * 2);  // contiguous pair
  Acat[1] = (unsigned short*)alloc((size_t)NODES * STR * 2);
  unsigned short* rawbf = (unsigned short*)alloc((size_t)2 * NODES * 256 * 2);
  unsigned char* xs8 = (unsigned char*)alloc((size_t)2 * NODES * 256);  // fp8 shadow
  unsigned short* xbf = (unsigned short*)alloc((size_t)2 * NODES * DIN * 2);
  unsigned short* Wt = (unsigned short*)alloc((size_t)4 * 256 * 1024 * 2);
  unsigned short* Wet = (unsigned short*)alloc((size_t)2 * 256 * DIN * 2);
  float* bsum = (float*)alloc(1024 * 4);
  // bucket aliases rawbf (8.65MB <= 20.5MB): consumed by k_scat2 before the first
  // layer-GEMM writes rawbf — stream-ordered, safe.
  unsigned* bucket = (unsigned*)rawbf;
  int* gbase = (int*)alloc((size_t)NREL * NRG * 4);
  // ---- contiguous zero region ----
  size_t zoff0 = off;
  int* gcur = (int*)alloc((size_t)NREL * NRG * 4);
  float* stats = (float*)alloc((size_t)2 * 2 * 512 * 4);
  float* pooled = (float*)alloc((size_t)2 * NGRAPH * 256 * 4);
  float* gcnt = (float*)alloc((size_t)2 * NGRAPH * 4);
  size_t zbytes = off - zoff0;
  hipMemsetAsync(ws + zoff0, 0, zbytes, stream);

  k_bin<<<dim3(EDGES / BINSLC, NREL), 256, 0, stream>>>(edge_index, bucket, gcur);
  k_base<<<1, 64, 0, stream>>>(gcur, gbase, rowoff);
  k_scat2<<<dim3(NRG, NREL), 256, 0, stream>>>(bucket, gcur, gbase, rowoff, csr16);

  k_xcvt<<<(2 * NODES * DIN / 4 + 255) / 256, 256, 0, stream>>>(x_vuln, x_patch, xbf);
  k_wtrans<<<dim3(64, 16, 4), dim3(16, 16), 0, stream>>>(W_l, W_r, Wt);
  k_wembt<<<dim3(8, 16, 2), dim3(16, 16), 0, stream>>>(W_emb, Wet);
  k_bsum<<<4, 256, 0, stream>>>(b_l, bsum);

  // embed both node types in one dispatch (writes bf16 seg3 + fp8 shadow)
  k_mfma<DIN, DIN, 1><<<dim3(640, 2), 256, 0, stream>>>(xbf, Wet, b_emb, nullptr,
                                                        Acat[0] + 768, xs8, nullptr);

  for (int layer = 0; layer < 2; ++layer) {
    k_agg<<<dim3(8, 313, 3), 256, 0, stream>>>(xs8, Acat[0], Acat[1], rowoff, csr16);
    k_mfma<1024, STR, 0><<<dim3(640, 2), 256, 0, stream>>>(
        Acat[0], Wt + (size_t)layer * 2 * 256 * 1024, bsum + layer * 512, rawbf,
        nullptr, nullptr, stats + layer * 1024);
    if (layer == 0)
      k_bnapply<<<dim3((NODES * 256 + 255) / 256, 2), 256, 0, stream>>>(
          rawbf, stats, gamma, beta, Acat[0] + 768, xs8);
  }

  k_pool<<<dim3(512, 2), 256, 0, stream>>>(rawbf, stats + 2 * 512, gamma + 2 * 256,
                                           beta + 2 * 256, Acat[0] + 768, batch_vuln,
                                           batch_patch, pooled, gcnt);
  k_final<<<NGRAPH, 256, 0, stream>>>(pooled, gcnt, W_out, b_out, (float*)d_out);
}